// Round 15
// baseline (588.361 us; speedup 1.0000x reference)
//
#include <hip/hip_runtime.h>
#include <hip/hip_bf16.h>

// Grouped GEMM: out[n,g,k] = sum_d x[n*8+g, d] * W[g, k, d]
// Round 15: R14 wave-specialization, B moved out of LDS into registers.
//  - cvt_w: W f32 -> bf16 FRAGMENT-ORDERED image: per (g,jt,kt64) 32 KiB =
//    32 frags (wc,n,ks) x 64 lanes x 16 B. Consumers load their 8 frags/tile
//    straight global->reg (coalesced 1 KiB/wave, L2-resident 2.1 MB/XCD),
//    prefetched after last use (counted wait across barrier). [R9-verified
//    pattern at BK=32, extended to BK=64.]
//  - Producers (4 waves) stage ONLY A: 8 f32x4 loads + cvt_pk + 8 linear
//    ds_write_b128, 2-deep A pipeline (R14-verified). No manual vmcnt needed.
//  - LDS 64 KiB (A dbuf only). Per-CU LDS/K-tile: 256->160 KB (< MFMA pipe).
//  - 12 waves via __launch_bounds__(768,3); consumers R14-verbatim otherwise.

namespace {

constexpr int NG   = 8;
constexpr int DIN  = 1024;
constexpr int DOUT = 1024;
constexpr int BM   = 256;
constexpr int BN   = 256;
constexpr int BK   = 64;
constexpr int NKT  = DIN / BK;            // 16
constexpr int ROWB = BK * 2;              // 128 B per A-LDS row
constexpr int TILE = BM * ROWB;           // 32 KiB A tile buffer
constexpr int JTN  = DOUT / BN;           // 4
constexpr int FRAGT = 32 * 1024;          // B frag-tile bytes per (g,jt,kt)
constexpr size_t WSB_BYTES = (size_t)NG * JTN * NKT * FRAGT;  // 16.78 MB

typedef __attribute__((ext_vector_type(8))) short bf16x8;
typedef __attribute__((ext_vector_type(4))) float f32x4;

__device__ __forceinline__ bf16x8 pack_bf16x8v(f32x4 lo, f32x4 hi) {
  union { __hip_bfloat162 h2[4]; bf16x8 v; } p;
  p.h2[0] = __float22bfloat162_rn(make_float2(lo.x, lo.y));
  p.h2[1] = __float22bfloat162_rn(make_float2(lo.z, lo.w));
  p.h2[2] = __float22bfloat162_rn(make_float2(hi.x, hi.y));
  p.h2[3] = __float22bfloat162_rn(make_float2(hi.z, hi.w));
  return p.v;
}

#define FENCE() asm volatile("" ::: "memory")
#define BAR()   do { FENCE(); __builtin_amdgcn_s_barrier(); FENCE(); } while (0)
#define LGKM0() asm volatile("s_waitcnt lgkmcnt(0)" ::: "memory")
#define MFMA_(a, b, c) __builtin_amdgcn_mfma_f32_16x16x32_bf16((a), (b), (c), 0, 0, 0)

// ---------------- cvt_w: W f32 -> bf16 fragment-ordered image ---------------
// one thread per 16-B granule. q -> tile(g,jt,kt) [2048 granules], frag
// f2 = (wc*4+n)*2+ks, lane l. Granule = W[g, jt*256+wc*64+n*16+(l&15),
//                                        kt*64+ks*32+(l>>4)*8 ..+8) as bf16x8.
__global__ __launch_bounds__(256)
void cvt_w_kernel(const float* __restrict__ W, char* __restrict__ wsB) {
  const int q    = (int)blockIdx.x * 256 + (int)threadIdx.x;
  const int tile = q >> 11;
  const int f2   = (q >> 6) & 31;
  const int l    = q & 63;
  const int g    = tile >> 6;
  const int jt   = (tile >> 4) & 3;
  const int kt   = tile & 15;
  const int wc   = f2 >> 3;
  const int n    = (f2 >> 1) & 3;
  const int ks   = f2 & 1;

  const int row = jt * BN + wc * 64 + n * 16 + (l & 15);
  const int col = kt * BK + ks * 32 + (l >> 4) * 8;
  const float* src = W + (size_t)(g * DOUT + row) * DIN + col;
  f32x4 lo = *(const f32x4*)(src);
  f32x4 hi = *(const f32x4*)(src + 4);
  *(bf16x8*)(wsB + (size_t)q * 16) = pack_bf16x8v(lo, hi);
}

// ---------------- producer helpers (A only) ---------------------------------
#define ISSUE_A(TT, CUR)                                                       \
  { const float* Ai = aSrc + (size_t)(TT) * BK;                                \
    _Pragma("unroll")                                                          \
    for (int p = 0; p < 8; ++p) {                                              \
      aL[CUR][2 * p]     = *(const f32x4*)(Ai + p * ARSTR);                    \
      aL[CUR][2 * p + 1] = *(const f32x4*)(Ai + p * ARSTR + 4);                \
    } }

#define WRITE_A(CUR, DBUF)                                                     \
  { _Pragma("unroll")                                                          \
    for (int p = 0; p < 8; ++p)                                                \
      *(bf16x8*)((DBUF) + dst0 + p * 4096) =                                   \
          pack_bf16x8v(aL[CUR][2 * p], aL[CUR][2 * p + 1]); }

// ---------------- gemm ------------------------------------------------------
template <bool WSB>
__global__ __launch_bounds__(768, 3)
void gemm_ws(const float* __restrict__ X, const float* __restrict__ W,
             const char* __restrict__ wsB, float* __restrict__ O) {
  extern __shared__ char smem[];
  char* const smA = smem;                  // [2][256][64] bf16, swizzled
  char* const smB = smem + 2 * TILE;       // fallback only (WSB=false)

  // ---- block mapping: group == XCD (1024 blocks, 128/XCD), bijective
  const int bid = (int)blockIdx.x;
  const int swz = (bid & 7) * 128 + (bid >> 3);
  const int jt = swz & 3;                  // col panel [0,4) fastest (X reuse)
  const int it = (swz >> 2) & 31;          // row tile  [0,32)
  const int g  = swz >> 7;                 // group     [0,8)  == XCD

  const int n0 = it * BM;
  const int c0 = jt * BN;

  const int tid  = (int)threadIdx.x;
  const int lane = tid & 63;
  const int wid  = tid >> 6;               // 0-7 consumers, 8-11 producers

  if (wid < 8) {
    // ================= consumers =================
    const int wr = (wid >> 2) & 1;
    const int wc = wid & 3;
    const int fr = lane & 15;
    const int fq = lane >> 4;
    const int colx0 = ((fq       ^ (fr & 7)) << 4);   // ks=0 granules 0-3
    const int colx1 = (((4 + fq) ^ (fr & 7)) << 4);   // ks=1 granules 4-7
    const int aRow0 = (wr * 128 + fr) * ROWB;
    const int bRow0 = (wc * 64  + fr) * ROWB;         // fallback LDS path

    // B fragment stream base (this wave's 8 KiB slice per K-tile)
    const char* BgF = wsB + (size_t)((g * JTN + jt) * NKT) * FRAGT
                          + (size_t)wc * 8 * 1024 + lane * 16;

    f32x4 acc[8][4];
#pragma unroll
    for (int m = 0; m < 8; ++m)
#pragma unroll
      for (int n = 0; n < 4; ++n) acc[m][n] = (f32x4){0.f, 0.f, 0.f, 0.f};

    bf16x8 bfr[4][2];
    if (WSB) {
#pragma unroll
      for (int n = 0; n < 4; ++n)
#pragma unroll
        for (int ks = 0; ks < 2; ++ks)
          bfr[n][ks] = *(const bf16x8*)(BgF + (n * 2 + ks) * 1024);
    }

    BAR();   // matches producer prologue barrier

    for (int t = 0; t < NKT; ++t) {
      char* const cA = smA + (t & 1) * TILE;
      char* const cB = smB + (t & 1) * TILE;   // fallback only
#pragma unroll
      for (int ks = 0; ks < 2; ++ks) {
        const int cx = ks ? colx1 : colx0;
        if (!WSB) {
#pragma unroll
          for (int n = 0; n < 4; ++n)
            bfr[n][ks] = *(const bf16x8*)(cB + bRow0 + n * 2048 + cx);
        }
        __builtin_amdgcn_s_setprio(1);
#pragma unroll
        for (int m = 0; m < 8; ++m) {
          bf16x8 am = *(const bf16x8*)(cA + aRow0 + m * 2048 + cx);
#pragma unroll
          for (int n = 0; n < 4; ++n)
            acc[m][n] = MFMA_(am, bfr[n][ks], acc[m][n]);
        }
        __builtin_amdgcn_s_setprio(0);
      }
      // prefetch next tile's B frags right after last use; the implicit
      // wait lands at first use in t+1 (counted, in flight across barrier)
      if (WSB && t + 1 < NKT) {
        const char* Bn = BgF + (size_t)(t + 1) * FRAGT;
#pragma unroll
        for (int n = 0; n < 4; ++n)
#pragma unroll
          for (int ks = 0; ks < 2; ++ks)
            bfr[n][ks] = *(const bf16x8*)(Bn + (n * 2 + ks) * 1024);
      }
      if (t + 1 < NKT) BAR();
    }

    // ---- epilogue: C/D layout col = lane&15, row = (lane>>4)*4 + reg (m89)
#pragma unroll
    for (int m = 0; m < 8; ++m) {
#pragma unroll
      for (int r = 0; r < 4; ++r) {
        const int row = wr * 128 + m * 16 + fq * 4 + r;
        float* orow = O + ((size_t)(n0 + row) * NG + g) * DOUT + c0 + wc * 64;
#pragma unroll
        for (int n = 0; n < 4; ++n) {
          orow[n * 16 + fr] = acc[m][n][r];
        }
      }
    }
  } else {
    // ================= producers (4 waves, 256 threads): A only ============
    const int ptid = tid - 512;            // 0..255
    const int r0   = ptid >> 3;            // base row 0..31 (+ p*32)
    const int sl   = ptid & 7;             // phys granule slot
    const int lg   = sl ^ (r0 & 7);        // logical k-granule (32%8==0)
    const int dst0 = ptid * 16;            // linear LDS dest

    const float* aSrc = X + ((size_t)(n0 + r0) * NG + g) * DIN + lg * 8;
    constexpr size_t ARSTR = (size_t)32 * NG * DIN;   // +32 tile rows
    const float* bSrc = W + ((size_t)(g * DOUT + c0 + r0)) * DIN + lg * 8;
    constexpr size_t BRSTR = (size_t)32 * DIN;

    f32x4 aL[2][16];

    if (WSB) {
      // ---- prologue: A(0)->aL[0], A(1)->aL[1]; write A(0); publish
      ISSUE_A(0, 0);
      ISSUE_A(1, 1);
      FENCE();
      WRITE_A(0, smA);                     // counted wait: A(1) in flight
      LGKM0();
      BAR();

      for (int t = 0; t + 1 < NKT; ++t) {
        char* const nA = smA + ((t + 1) & 1) * TILE;
        const int cur = t & 1;             // buffer loaded 2 tiles ago = t+1
        if (t + 2 < NKT) ISSUE_A(t + 2, cur);
        FENCE();
        WRITE_A(cur ^ 1, nA);              // A(t+1); counted wait (A(t+2) out)
        LGKM0();
        BAR();
      }
      // 1 + 15 barriers == consumer's 16.
    } else {
      // ---- fallback (no ws): 1-deep reg-staged A and B into LDS
      f32x4 bL[16];
#pragma unroll
      for (int p = 0; p < 8; ++p) {
        aL[0][2 * p]     = *(const f32x4*)(aSrc + p * ARSTR);
        aL[0][2 * p + 1] = *(const f32x4*)(aSrc + p * ARSTR + 4);
        bL[2 * p]        = *(const f32x4*)(bSrc + p * BRSTR);
        bL[2 * p + 1]    = *(const f32x4*)(bSrc + p * BRSTR + 4);
      }
      WRITE_A(0, smA);
#pragma unroll
      for (int p = 0; p < 8; ++p)
        *(bf16x8*)(smB + dst0 + p * 4096) =
            pack_bf16x8v(bL[2 * p], bL[2 * p + 1]);
      LGKM0();
      BAR();
      for (int t = 0; t + 1 < NKT; ++t) {
        char* const nA = smA + ((t + 1) & 1) * TILE;
        char* const nB = smB + ((t + 1) & 1) * TILE;
        const float* Ai = aSrc + (size_t)(t + 1) * BK;
        const float* Bi = bSrc + (size_t)(t + 1) * BK;
#pragma unroll
        for (int p = 0; p < 8; ++p) {
          aL[0][2 * p]     = *(const f32x4*)(Ai + p * ARSTR);
          aL[0][2 * p + 1] = *(const f32x4*)(Ai + p * ARSTR + 4);
          bL[2 * p]        = *(const f32x4*)(Bi + p * BRSTR);
          bL[2 * p + 1]    = *(const f32x4*)(Bi + p * BRSTR + 4);
        }
        WRITE_A(0, nA);
#pragma unroll
        for (int p = 0; p < 8; ++p)
          *(bf16x8*)(nB + dst0 + p * 4096) =
              pack_bf16x8v(bL[2 * p], bL[2 * p + 1]);
        LGKM0();
        BAR();
      }
    }
  }
}

} // namespace

extern "C" void kernel_launch(void* const* d_in, const int* in_sizes, int n_in,
                              void* d_out, int out_size, void* d_ws, size_t ws_size,
                              hipStream_t stream) {
  (void)n_in; (void)out_size;
  const float* X = (const float*)d_in[0];
  const float* W = (const float*)d_in[1];
  float* O = (float*)d_out;

  const int tokens_total = in_sizes[0] / DIN;            // 65536
  const int ntok_per_g   = tokens_total / NG;            // 8192
  const int grid = NG * (ntok_per_g / BM) * (DOUT / BN); // 1024

  if (ws_size >= WSB_BYTES) {
    const int cvt_grid = (int)(WSB_BYTES / 16 / 256);    // 4096
    cvt_w_kernel<<<dim3(cvt_grid), dim3(256), 0, stream>>>(W, (char*)d_ws);
    const int lds = 2 * TILE;                            // 64 KiB (A only)
    (void)hipFuncSetAttribute((const void*)gemm_ws<true>,
                              hipFuncAttributeMaxDynamicSharedMemorySize, lds);
    gemm_ws<true><<<dim3(grid), dim3(768), lds, stream>>>(
        X, W, (const char*)d_ws, O);
  } else {
    const int lds = 4 * TILE;                            // 128 KiB (A+B)
    (void)hipFuncSetAttribute((const void*)gemm_ws<false>,
                              hipFuncAttributeMaxDynamicSharedMemorySize, lds);
    gemm_ws<false><<<dim3(grid), dim3(768), lds, stream>>>(
        X, W, nullptr, O);
  }
}